// Round 2
// baseline (162.390 us; speedup 1.0000x reference)
//
#include <hip/hip_runtime.h>

#define ROWS   32768      // 8*4096 indices
#define DIM4   128        // 512 floats per row = 128 float4
#define BLOCK  256
#define TPR    32         // threads per row (each thread: 4 float4, cols c, c+32, c+64, c+96)

typedef float f4 __attribute__((ext_vector_type(4)));   // native vector type: nontemporal-builtin legal

__global__ __launch_bounds__(BLOCK) void embed_gather_kernel(
    const int* __restrict__ idx,
    const f4* __restrict__ W,
    f4* __restrict__ out)
{
    const int t   = blockIdx.x * BLOCK + threadIdx.x;
    const int row = t >> 5;          // 32 threads per output row
    const int c   = t & 31;          // base col in float4 units

    const int id  = idx[row];        // one dependent load, then 4 independent loads

    const f4* __restrict__ src = W   + (size_t)id  * DIM4 + c;
    f4*       __restrict__ dst = out + (size_t)row * DIM4 + c;

    // 4 independent 16B loads in flight per thread (MLP=4), coalesced:
    // per instruction a wave covers two contiguous 512B segments.
    f4 v0 = src[0];
    f4 v1 = src[32];
    f4 v2 = src[64];
    f4 v3 = src[96];

    // out is write-once streaming data: keep it out of L2 so W row-repeats stay cached.
    __builtin_nontemporal_store(v0, dst);
    __builtin_nontemporal_store(v1, dst + 32);
    __builtin_nontemporal_store(v2, dst + 64);
    __builtin_nontemporal_store(v3, dst + 96);
}

extern "C" void kernel_launch(void* const* d_in, const int* in_sizes, int n_in,
                              void* d_out, int out_size, void* d_ws, size_t ws_size,
                              hipStream_t stream) {
    const int* idx = (const int*)d_in[0];
    const f4*  W   = (const f4*)d_in[1];
    f4*        out = (f4*)d_out;

    const int grid = ROWS * TPR / BLOCK;      // 4096 blocks, exact
    embed_gather_kernel<<<grid, BLOCK, 0, stream>>>(idx, W, out);
}